// Round 11
// baseline (227.184 us; speedup 1.0000x reference)
//
#include <hip/hip_runtime.h>
#include <cstdint>
#include <cstddef>

// Problem constants (B=2, M=32, D=64, T=2048, F=16, L=512, S=32768)
#define DAMP 0.9998f

typedef __attribute__((ext_vector_type(8))) short bf16x8;
typedef __attribute__((ext_vector_type(8))) unsigned short u16x8;
typedef __attribute__((ext_vector_type(4))) float f32x4;

__device__ __forceinline__ unsigned short f2bf(float x) {
    unsigned u = __float_as_uint(x);
    unsigned r = (u + 0x7FFFu + ((u >> 16) & 1u)) >> 16;   // RNE
    return (unsigned short)r;
}
__device__ __forceinline__ float bf2f(unsigned short v) {
    return __uint_as_float((unsigned)v << 16);
}

// ---------------------------------------------------------------------------
// threefry2x32, JAX partitionable mode. key=(0,1); counter (0, j); o0^o1.
// [verified r4]
// ---------------------------------------------------------------------------
__device__ __forceinline__ void threefry_0j(unsigned j, unsigned& o0, unsigned& o1) {
    unsigned x0 = 0u;
    unsigned x1 = j + 1u;
    const unsigned ks2 = 0x1BD11BDBu;
#define TFR(r) { x0 += x1; x1 = (x1 << (r)) | (x1 >> (32 - (r))); x1 ^= x0; }
    TFR(13) TFR(15) TFR(26) TFR(6)
    x0 += 1u;   x1 += ks2 + 1u;
    TFR(17) TFR(29) TFR(16) TFR(24)
    x0 += ks2;  x1 += 0u + 2u;
    TFR(13) TFR(15) TFR(26) TFR(6)
    /*x0+=0*/   x1 += 1u + 3u;
    TFR(17) TFR(29) TFR(16) TFR(24)
    x0 += 1u;   x1 += ks2 + 4u;
    TFR(13) TFR(15) TFR(26) TFR(6)
    x0 += ks2;  x1 += 0u + 5u;
#undef TFR
    o0 = x0; o1 = x1;
}

__device__ __forceinline__ float noise_at(unsigned j) {
    unsigned o0, o1;
    threefry_0j(j, o0, o1);
    unsigned bits = o0 ^ o1;
    float u = __uint_as_float((bits >> 9) | 0x3F800000u) - 1.0f;
    return fmaxf(-1.0f, u * 2.0f - 1.0f);
}

// Dir(u) = sin(2049*pi*u/32768)/sin(pi*u/32768), Dir(0)=2049, period 32768.
__device__ __forceinline__ float dir_val(unsigned u) {
    if (u == 0u) return 2049.f;
    const float PIO = 9.58737992e-05f;
    unsigned y = (2049u * u) & 65535u;
    float sgn = 1.f;
    if (y >= 32768u) { y -= 32768u; sgn = -1.f; }
    unsigned yy = (y > 16384u) ? (32768u - y) : y;
    float sy = sgn * sinf((float)yy * PIO);
    unsigned uu = (u > 16384u) ? (32768u - u) : u;
    float su = sinf((float)uu * PIO);
    return sy / su;
}

// ---------------------------------------------------------------------------
// K0: tables — blocks 0..127: DirRev bf16; blocks 128..159: normalized
// reversed filters bf16.
// ---------------------------------------------------------------------------
__global__ void tables_kernel(const float* __restrict__ filters,
                              unsigned short* __restrict__ dirrev,
                              unsigned short* __restrict__ fnrev) {
    const int tid = threadIdx.x;
    if (blockIdx.x < 128) {
        const unsigned i = blockIdx.x * 256 + tid;
        const unsigned p = i >> 11, k = i & 2047u;
        dirrev[i] = f2bf(dir_val(16u * (2047u - k) + p));
    } else if (tid < 64) {
        const int row = blockIdx.x - 128;
        const float* src = filters + (size_t)row * 512;
        float s = 0.f;
        for (int i = tid; i < 512; i += 64) { const float v = src[i]; s += v * v; }
        #pragma unroll
        for (int off = 32; off; off >>= 1) s += __shfl_xor(s, off);
        const float scale = 1.f / (sqrtf(s) + 1e-8f);
        for (int i = tid; i < 512; i += 64)
            fnrev[(size_t)row * 512 + i] = f2bf(src[511 - i] * scale);
    }
}

// ---------------------------------------------------------------------------
// K1: fused sim — one block per bm (64 blocks x 1024 threads).
// thread = (chunk c = tid>>6 of 128 steps, d = tid&63).
// Phase A: local 128-step run from zero state (per-thread float4 streaming,
//          each thread's walk keeps its own L1 lines hot; overfetch = 1).
// Phase B: in-block scan: entry state via fp64 A^128 (7 squarings) +
//          <=15 affine compositions through an 8 KB LDS exchange.
// Phase C: emit 128 steps with exact reference ops; disp via per-thread
//          float4 stores; rec via 6-shfl butterfly + lane-select.
// ---------------------------------------------------------------------------
__global__ __launch_bounds__(1024) void sim_fused(const float* __restrict__ forces,
                                                  const float* __restrict__ hmod,
                                                  const float* __restrict__ home,
                                                  const float* __restrict__ masses,
                                                  const float* __restrict__ tensions,
                                                  const float* __restrict__ gains,
                                                  const float* __restrict__ mics,
                                                  float* __restrict__ disp,
                                                  float* __restrict__ rec) {
    const int bm = blockIdx.x;
    const int m = bm & 31;
    const int tid = threadIdx.x;
    const int c = tid >> 6;          // chunk 0..15
    const int d = tid & 63;
    const int t0 = c * 128;
    const float k = tensions[m * 64 + d] / masses[m];
    const float gain = gains[m];
    const float mic = mics[m * 64 + d];
    const float hd = home[d];
    const size_t rowoff = ((size_t)bm * 64 + d) * 2048 + t0;
    const float* fp = forces + rowoff;
    const float* hp = hmod + rowoff;

    __shared__ float wsh[16][2][64];

    // ---- phase A: local run from zero state ----
    float pos = 0.f, vel = 0.f;
    for (int j = 0; j < 128; j += 4) {
        const float4 fv = *(const float4*)(fp + j);
        const float4 hv = *(const float4*)(hp + j);
        #pragma unroll
        for (int q = 0; q < 4; ++q) {
            const float f = ((const float*)&fv)[q];
            const float h = hd + ((const float*)&hv)[q];
            const float dir = h - pos;
            const float acc = f + k * dir;
            vel = (vel + acc) * DAMP;
            pos = pos + vel;
        }
    }
    wsh[c][0][d] = pos;
    wsh[c][1][d] = vel;
    __syncthreads();

    // ---- phase B: fp64 scan for chunk-entry state ----
    {
        const double kd = (double)k, cd = (double)DAMP;
        double Ma = 1.0 - cd * kd, Mb = cd, Mc = -cd * kd, Md = cd;
        #pragma unroll
        for (int it = 0; it < 7; ++it) {          // A^(2^7) = A^128
            const double na = Ma * Ma + Mb * Mc;
            const double nb = Ma * Mb + Mb * Md;
            const double nc = Mc * Ma + Md * Mc;
            const double nd = Mc * Mb + Md * Md;
            Ma = na; Mb = nb; Mc = nc; Md = nd;
        }
        double pd = 0.0, vd = 0.0;
        for (int cc = 0; cc < c; ++cc) {
            const double wp = (double)wsh[cc][0][d];
            const double wv = (double)wsh[cc][1][d];
            const double np = Ma * pd + Mb * vd + wp;
            const double nv = Mc * pd + Md * vd + wv;
            pd = np; vd = nv;
        }
        pos = (float)pd; vel = (float)vd;
    }

    // ---- phase C: emit (exact reference step ops) ----
    for (int half = 0; half < 2; ++half) {
        float keep = 0.f;
        for (int j0 = 0; j0 < 64; j0 += 4) {
            const int j = half * 64 + j0;
            const float4 fv = *(const float4*)(fp + j);
            const float4 hv = *(const float4*)(hp + j);
            float4 dv;
            #pragma unroll
            for (int q = 0; q < 4; ++q) {
                const float f = ((const float*)&fv)[q];
                const float h = hd + ((const float*)&hv)[q];
                const float dir = h - pos;
                const float acc = f + k * dir;
                vel = (vel + acc) * DAMP;
                pos = pos + vel;
                ((float*)&dv)[q] = dir;
                const float x = vel * gain;
                const float e = __expf(2.f * x);
                float sum = (1.f - 2.f / (e + 1.f)) * mic;
                #pragma unroll
                for (int off = 1; off < 64; off <<= 1) sum += __shfl_xor(sum, off);
                keep = ((j0 + q) == d) ? sum : keep;
            }
            *(float4*)(disp + rowoff + j) = dv;
        }
        rec[(size_t)bm * 2048 + t0 + half * 64 + d] = keep;
    }
}

// ---------------------------------------------------------------------------
// K2: mixture (fp32 acc -> bf16). [unchanged]
// ---------------------------------------------------------------------------
__global__ __launch_bounds__(256) void mix_kernel(const float* __restrict__ disp,
                                                  const float* __restrict__ tofm,
                                                  unsigned short* __restrict__ mixture) {
    __shared__ __align__(16) float tf[64][16];
    const int tid = threadIdx.x;
    for (int i = tid; i < 1024; i += 256) tf[i >> 4][i & 15] = tofm[i];
    __syncthreads();
    const int bm = blockIdx.y;
    const int t = blockIdx.x * 256 + tid;
    float acc[16];
    #pragma unroll
    for (int f = 0; f < 16; ++f) acc[f] = 0.f;
    for (int d = 0; d < 64; ++d) {
        const float v = disp[((size_t)bm * 64 + d) * 2048 + t];
        const float4* r4 = (const float4*)tf[d];
        const float4 a4 = r4[0], b4 = r4[1], c4 = r4[2], d4 = r4[3];
        acc[0]  += v * a4.x; acc[1]  += v * a4.y; acc[2]  += v * a4.z; acc[3]  += v * a4.w;
        acc[4]  += v * b4.x; acc[5]  += v * b4.y; acc[6]  += v * b4.z; acc[7]  += v * b4.w;
        acc[8]  += v * c4.x; acc[9]  += v * c4.y; acc[10] += v * c4.z; acc[11] += v * c4.w;
        acc[12] += v * d4.x; acc[13] += v * d4.y; acc[14] += v * d4.z; acc[15] += v * d4.w;
    }
    #pragma unroll
    for (int f = 0; f < 16; ++f)
        mixture[((size_t)bm * 16 + f) * 2048 + t] = f2bf(acc[f]);
}

// ---------------------------------------------------------------------------
// K3 (MFMA): fft_resample. [unchanged r7]
// ---------------------------------------------------------------------------
#define DR_STRIDE 4112u
#define W_STRIDE  5136u
#define W_OFF     65792u
#define RS_SMEM   106880u

__global__ __launch_bounds__(256) void resample_kernel(const float* __restrict__ rec,
                                                       const unsigned short* __restrict__ dirrev,
                                                       float* __restrict__ up) {
    const int bm = blockIdx.x;
    const int Q0 = blockIdx.y * 512;
    const int tid = threadIdx.x;
    __shared__ __align__(16) unsigned char smem[RS_SMEM];

    for (int i = tid; i < 4096; i += 256) {
        const int p = i >> 8, c16 = i & 255;
        *(uint4*)(smem + (unsigned)p * DR_STRIDE + 16u * c16) = ((const uint4*)dirrev)[i];
    }
    for (int x = tid; x < 2560; x += 256) {
        const int g = (Q0 + x + 1) & 2047;
        const unsigned short bv = f2bf(rec[(size_t)bm * 2048 + g]);
        #pragma unroll
        for (int sg = 0; sg < 8; ++sg) {
            const int y = x - sg;
            if (y >= 0) *(unsigned short*)(smem + W_OFF + sg * W_STRIDE + 2 * y) = bv;
        }
    }
    __syncthreads();

    const int lane = tid & 63;
    const int wv = tid >> 6;
    const int i15 = lane & 15;
    const int g4 = lane >> 4;

    f32x4 acc[8];
    #pragma unroll
    for (int i = 0; i < 8; ++i) acc[i] = (f32x4){0.f, 0.f, 0.f, 0.f};

    const unsigned abase = (unsigned)i15 * DR_STRIDE + 16u * g4;
    const unsigned bbase = W_OFF + (unsigned)(i15 & 7) * W_STRIDE + 16u * (i15 >> 3) + 16u * g4;

    for (int kkb = 0; kkb < 8; ++kkb) {
        bf16x8 afr[8];
        #pragma unroll
        for (int kj = 0; kj < 8; ++kj)
            afr[kj] = *(const bf16x8*)(smem + abase + 64u * (kkb * 8 + kj));
        #pragma unroll
        for (int qtl = 0; qtl < 8; ++qtl) {
            const int qt = wv * 8 + qtl;
            const unsigned bb = bbase + 32u * qt;
            #pragma unroll
            for (int kj = 0; kj < 8; ++kj) {
                const bf16x8 bfr = *(const bf16x8*)(smem + bb + 64u * (kkb * 8 + kj));
                acc[qtl] = __builtin_amdgcn_mfma_f32_16x16x32_bf16(afr[kj], bfr, acc[qtl], 0, 0, 0);
            }
        }
    }

    #pragma unroll
    for (int qtl = 0; qtl < 8; ++qtl) {
        const int qt = wv * 8 + qtl;
        const int q = Q0 + 16 * qt + i15;
        const int sbase = 16 * q + 4 * g4;
        const unsigned jb = (unsigned)bm * 32768u + (unsigned)sbase;
        float4 o;
        o.x = fabsf(acc[qtl][0] * (1.f / 8192.f)) * noise_at(jb);
        o.y = fabsf(acc[qtl][1] * (1.f / 8192.f)) * noise_at(jb + 1u);
        o.z = fabsf(acc[qtl][2] * (1.f / 8192.f)) * noise_at(jb + 2u);
        o.w = fabsf(acc[qtl][3] * (1.f / 8192.f)) * noise_at(jb + 3u);
        *(float4*)(up + (size_t)bm * 32768 + sbase) = o;
    }
}

// ---------------------------------------------------------------------------
// K4 (MFMA): hf — window re-based to S0-512 (aligned), vectorized 8-copy
// staging (ushort8 b128 writes). grid (32 s-tiles of 1024, 64 bm), 256 thr.
// B element for (rho,g,i15,g4,k): W[256g + (rho+1) + 16*i15 + k],
// sig=(rho+1)&7 picks copy, (rho+1-sig) in {0,8,16} -> byte {0,16,32}.
// ---------------------------------------------------------------------------
#define W_STR2   3216u            // >= 3104 needed, == 16 mod 128
#define MX_OFF   25728u           // 8*3216
#define HF_SMEM  27904u           // + 16*68*2

__global__ __launch_bounds__(256) void hf_kernel(const float* __restrict__ up,
                                                 const unsigned short* __restrict__ fnrev,
                                                 const unsigned short* __restrict__ mixture,
                                                 float* __restrict__ hf) {
    const int tile = blockIdx.x;
    const int bm = blockIdx.y;
    const int b = bm >> 5;
    const int S0 = tile * 1024;
    const int tbase = tile * 64 - 1;
    const int tid = threadIdx.x;

    __shared__ __align__(16) unsigned char smem[HF_SMEM];
    unsigned short* mixl = (unsigned short*)(smem + MX_OFF);

    // stage 8 shifted copies, vectorized: group gy covers W[8gy .. 8gy+15],
    // W[x] = up[S0-512+x]; copy sg gets ushort8 = W[8gy+sg .. 8gy+sg+8)
    for (int gy = tid; gy < 194; gy += 256) {
        const int gbase = S0 - 512 + 8 * gy;
        unsigned short wv[16];
        if (gbase >= 0 && gbase + 16 <= 32768) {
            const float4* src = (const float4*)(up + (size_t)bm * 32768 + gbase);
            #pragma unroll
            for (int qq = 0; qq < 4; ++qq) {
                const float4 v4 = src[qq];
                wv[qq * 4 + 0] = f2bf(v4.x); wv[qq * 4 + 1] = f2bf(v4.y);
                wv[qq * 4 + 2] = f2bf(v4.z); wv[qq * 4 + 3] = f2bf(v4.w);
            }
        } else {
            #pragma unroll
            for (int qq = 0; qq < 16; ++qq) {
                const int gi = gbase + qq;
                wv[qq] = (gi >= 0 && gi < 32768) ? f2bf(up[(size_t)bm * 32768 + gi])
                                                 : (unsigned short)0;
            }
        }
        #pragma unroll
        for (int sg = 0; sg < 8; ++sg) {
            u16x8 o;
            #pragma unroll
            for (int j = 0; j < 8; ++j) o[j] = wv[sg + j];
            *(u16x8*)(smem + sg * W_STR2 + 16 * gy) = o;
        }
    }
    for (int i = tid; i < 16 * 66; i += 256) {
        const int f = i / 66, tt = i - f * 66;
        const int t = tbase + tt;
        mixl[f * 68 + tt] = (t >= 0 && t < 2048)
            ? mixture[((size_t)bm * 16 + f) * 2048 + t] : (unsigned short)0;
    }
    const int lane = tid & 63;
    const int i15 = lane & 15;
    const int g4 = lane >> 4;
    const int wv = tid >> 6;
    bf16x8 afr[16];
    #pragma unroll
    for (int kk = 0; kk < 16; ++kk)
        afr[kk] = *(const bf16x8*)(fnrev + (size_t)(b * 16 + i15) * 512 + 32 * kk + 8 * g4);
    __syncthreads();

    for (int rr = 0; rr < 4; ++rr) {
        const int rho = wv * 4 + rr;
        const int rp1 = rho + 1;
        const int sig = rp1 & 7;
        const unsigned baseR = (unsigned)sig * W_STR2 + 2u * (rp1 - sig)
                             + 32u * i15 + 16u * g4;
        #pragma unroll
        for (int g = 0; g < 4; ++g) {
            f32x4 acc = {0.f, 0.f, 0.f, 0.f};
            const unsigned tb = baseR + 512u * g;
            #pragma unroll
            for (int kk = 0; kk < 16; ++kk) {
                const bf16x8 bfr = *(const bf16x8*)(smem + tb + 64u * kk);
                acc = __builtin_amdgcn_mfma_f32_16x16x32_bf16(afr[kk], bfr, acc, 0, 0, 0);
            }
            const int s = S0 + 256 * g + rho + 16 * i15;
            float posf = ((float)s + 0.5f) * 0.0625f - 0.5f;
            posf = fminf(fmaxf(posf, 0.f), 2047.f);
            const int i0 = (int)posf;
            const float wg = posf - (float)i0;
            const int i1 = min(i0 + 1, 2047);
            const int t0 = i0 - tbase, t1 = i1 - tbase;
            float part = 0.f;
            #pragma unroll
            for (int r = 0; r < 4; ++r) {
                const int f = 4 * g4 + r;
                const float mv = bf2f(mixl[f * 68 + t0]) * (1.f - wg)
                               + bf2f(mixl[f * 68 + t1]) * wg;
                part += mv * acc[r];
            }
            part += __shfl_xor(part, 16);
            part += __shfl_xor(part, 32);
            if (g4 == 0) {
                const int e = 512 + 256 * g + rho + 16 * i15;   // copy-0 element
                const float upv = bf2f(*(const unsigned short*)(smem + 2 * e));
                hf[(size_t)bm * 32768 + s] = part + upv;
            }
        }
    }
}

// ---------------------------------------------------------------------------
// Launch
// ---------------------------------------------------------------------------
extern "C" void kernel_launch(void* const* d_in, const int* in_sizes, int n_in,
                              void* d_out, int out_size, void* d_ws, size_t ws_size,
                              hipStream_t stream) {
    const float* forces   = (const float*)d_in[0];
    const float* hmod     = (const float*)d_in[1];
    const float* filters  = (const float*)d_in[2];
    const float* home     = (const float*)d_in[3];
    const float* masses   = (const float*)d_in[4];
    const float* tensions = (const float*)d_in[5];
    const float* gains    = (const float*)d_in[6];
    const float* mics     = (const float*)d_in[7];
    const float* tofm     = (const float*)d_in[8];

    float* out  = (float*)d_out;
    float* rec  = out;                  // 131072
    float* disp = out + 131072;         // 8388608
    float* hf   = out + 8519680;        // 2097152

    float* up               = (float*)d_ws;                             // 2097152 f32
    unsigned short* mixture = (unsigned short*)((float*)d_ws + 2097152);// 2097152 bf16
    unsigned short* dirrev  = (unsigned short*)((float*)d_ws + 3145728);// 32768 bf16
    unsigned short* fnrev   = (unsigned short*)((float*)d_ws + 3162112);// 16384 bf16
    // total ws use ~12.7 MB

    tables_kernel<<<160, 256, 0, stream>>>(filters, dirrev, fnrev);
    sim_fused<<<64, 1024, 0, stream>>>(forces, hmod, home, masses, tensions, gains, mics, disp, rec);
    mix_kernel<<<dim3(8, 64), 256, 0, stream>>>(disp, tofm, mixture);
    resample_kernel<<<dim3(64, 4), 256, 0, stream>>>(rec, dirrev, up);
    hf_kernel<<<dim3(32, 64), 256, 0, stream>>>(up, fnrev, mixture, hf);
}

// Round 13
// 129.173 us; speedup vs baseline: 1.7588x; 1.7588x over previous
//
#include <hip/hip_runtime.h>
#include <cstdint>
#include <cstddef>

// Problem constants (B=2, M=32, D=64, T=2048, F=16, L=512, S=32768)
#define DAMP 0.9998f

typedef __attribute__((ext_vector_type(8))) short bf16x8;
typedef __attribute__((ext_vector_type(4))) float f32x4;

__device__ __forceinline__ unsigned short f2bf(float x) {
    unsigned u = __float_as_uint(x);
    unsigned r = (u + 0x7FFFu + ((u >> 16) & 1u)) >> 16;   // RNE
    return (unsigned short)r;
}
__device__ __forceinline__ float bf2f(unsigned short v) {
    return __uint_as_float((unsigned)v << 16);
}

// ---------------------------------------------------------------------------
// threefry2x32, JAX partitionable mode. key=(0,1); counter (0, j); o0^o1.
// [verified r4]
// ---------------------------------------------------------------------------
__device__ __forceinline__ void threefry_0j(unsigned j, unsigned& o0, unsigned& o1) {
    unsigned x0 = 0u;
    unsigned x1 = j + 1u;
    const unsigned ks2 = 0x1BD11BDBu;
#define TFR(r) { x0 += x1; x1 = (x1 << (r)) | (x1 >> (32 - (r))); x1 ^= x0; }
    TFR(13) TFR(15) TFR(26) TFR(6)
    x0 += 1u;   x1 += ks2 + 1u;
    TFR(17) TFR(29) TFR(16) TFR(24)
    x0 += ks2;  x1 += 0u + 2u;
    TFR(13) TFR(15) TFR(26) TFR(6)
    /*x0+=0*/   x1 += 1u + 3u;
    TFR(17) TFR(29) TFR(16) TFR(24)
    x0 += 1u;   x1 += ks2 + 4u;
    TFR(13) TFR(15) TFR(26) TFR(6)
    x0 += ks2;  x1 += 0u + 5u;
#undef TFR
    o0 = x0; o1 = x1;
}

__device__ __forceinline__ float noise_at(unsigned j) {
    unsigned o0, o1;
    threefry_0j(j, o0, o1);
    unsigned bits = o0 ^ o1;
    float u = __uint_as_float((bits >> 9) | 0x3F800000u) - 1.0f;
    return fmaxf(-1.0f, u * 2.0f - 1.0f);
}

// Dir(u) = sin(2049*pi*u/32768)/sin(pi*u/32768), Dir(0)=2049, period 32768.
__device__ __forceinline__ float dir_val(unsigned u) {
    if (u == 0u) return 2049.f;
    const float PIO = 9.58737992e-05f;
    unsigned y = (2049u * u) & 65535u;
    float sgn = 1.f;
    if (y >= 32768u) { y -= 32768u; sgn = -1.f; }
    unsigned yy = (y > 16384u) ? (32768u - y) : y;
    float sy = sgn * sinf((float)yy * PIO);
    unsigned uu = (u > 16384u) ? (32768u - u) : u;
    float su = sinf((float)uu * PIO);
    return sy / su;
}

// ---------------------------------------------------------------------------
// K0: tables — blocks 0..127: DirRev bf16; blocks 128..159: normalized
// reversed filters bf16.
// ---------------------------------------------------------------------------
__global__ void tables_kernel(const float* __restrict__ filters,
                              unsigned short* __restrict__ dirrev,
                              unsigned short* __restrict__ fnrev) {
    const int tid = threadIdx.x;
    if (blockIdx.x < 128) {
        const unsigned i = blockIdx.x * 256 + tid;
        const unsigned p = i >> 11, k = i & 2047u;
        dirrev[i] = f2bf(dir_val(16u * (2047u - k) + p));
    } else if (tid < 64) {
        const int row = blockIdx.x - 128;
        const float* src = filters + (size_t)row * 512;
        float s = 0.f;
        for (int i = tid; i < 512; i += 64) { const float v = src[i]; s += v * v; }
        #pragma unroll
        for (int off = 32; off; off >>= 1) s += __shfl_xor(s, off);
        const float scale = 1.f / (sqrtf(s) + 1e-8f);
        for (int i = tid; i < 512; i += 64)
            fnrev[(size_t)row * 512 + i] = f2bf(src[511 - i] * scale);
    }
}

// ---------------------------------------------------------------------------
// K1a: sim pass 1 — 32-step chunk local affine constant w_c (from zero state).
// grid 4096 (bm*64+c), 64 threads. g-tile [64][33] = 8.4 KB.  [r10-verified]
// ---------------------------------------------------------------------------
__global__ __launch_bounds__(64) void sim_pass1(const float* __restrict__ forces,
                                                const float* __restrict__ hmod,
                                                const float* __restrict__ home,
                                                const float* __restrict__ masses,
                                                const float* __restrict__ tensions,
                                                float* __restrict__ w) {
    const int blk = blockIdx.x;
    const int bm = blk >> 6, c = blk & 63;
    const int m = bm & 31;
    const int d = threadIdx.x;
    const int t0 = c * 32;
    __shared__ float kv[64];
    __shared__ float hv[64];
    __shared__ __align__(16) float gt[64][33];
    kv[d] = tensions[m * 64 + d] / masses[m];
    hv[d] = home[d];
    __syncthreads();
    for (int i = d; i < 512; i += 64) {
        const int dd = i >> 3, q = (i & 7) * 4;
        const size_t off = ((size_t)bm * 64 + dd) * 2048 + t0 + q;
        const float4 fv = *(const float4*)(forces + off);
        const float4 hm = *(const float4*)(hmod + off);
        const float kk = kv[dd], hh = hv[dd];
        float4 g;
        g.x = fmaf(kk, hh + hm.x, fv.x);
        g.y = fmaf(kk, hh + hm.y, fv.y);
        g.z = fmaf(kk, hh + hm.z, fv.z);
        g.w = fmaf(kk, hh + hm.w, fv.w);
        *(float4*)&gt[dd][q] = g;
    }
    __syncthreads();
    const float k = kv[d];
    float pos = 0.f, vel = 0.f;
    #pragma unroll 8
    for (int ts = 0; ts < 32; ++ts) {
        const float acc = fmaf(-k, pos, gt[d][ts]);
        vel = (vel + acc) * DAMP;
        pos = pos + vel;
    }
    float* wrow = w + (size_t)blk * 128;
    wrow[d] = pos; wrow[64 + d] = vel;
}

// ---------------------------------------------------------------------------
// K1b: sim scan — fp64 A^32, serial scan over 64 chunks per (bm,d).
// IN PLACE: reads w[c], overwrites the slot with the chunk-ENTRY state.
// grid 64 (bm), 64 threads (d).  [r10-verified]
// ---------------------------------------------------------------------------
__global__ __launch_bounds__(64) void sim_scan(const float* __restrict__ masses,
                                               const float* __restrict__ tensions,
                                               float* __restrict__ w) {
    const int bm = blockIdx.x;
    const int m = bm & 31;
    const int d = threadIdx.x;
    const double kd = (double)(tensions[m * 64 + d] / masses[m]);
    const double cd = (double)DAMP;
    double Ma = 1.0 - cd * kd, Mb = cd, Mc = -cd * kd, Md = cd;
    #pragma unroll
    for (int it = 0; it < 5; ++it) {             // A^(2^5) = A^32
        const double na = Ma * Ma + Mb * Mc;
        const double nb = Ma * Mb + Mb * Md;
        const double nc = Mc * Ma + Md * Mc;
        const double nd = Mc * Mb + Md * Md;
        Ma = na; Mb = nb; Mc = nc; Md = nd;
    }
    double pos = 0.0, vel = 0.0;
    float* wb = w + (size_t)bm * 64 * 128;
    for (int c = 0; c < 64; ++c) {
        float* row = wb + c * 128;
        const double wp = (double)row[d];
        const double wv = (double)row[64 + d];
        row[d] = (float)pos;                     // entry state of chunk c
        row[64 + d] = (float)vel;
        const double np = Ma * pos + Mb * vel + wp;
        const double nv = Mc * pos + Md * vel + wv;
        pos = np; vel = nv;
    }
}

// ---------------------------------------------------------------------------
// K1c: sim pass 2 — 32-step emit from precomputed entry state, two 16-ts
// quarter stages. LDS 8.9 KB.  [r10-verified]
// ---------------------------------------------------------------------------
__global__ __launch_bounds__(64) void sim_pass2(const float* __restrict__ forces,
                                                const float* __restrict__ hmod,
                                                const float* __restrict__ home,
                                                const float* __restrict__ masses,
                                                const float* __restrict__ tensions,
                                                const float* __restrict__ gains,
                                                const float* __restrict__ mics,
                                                const float* __restrict__ w,
                                                float* __restrict__ disp,
                                                float* __restrict__ rec) {
    const int blk = blockIdx.x;
    const int bm = blk >> 6, c = blk & 63;
    const int m = bm & 31;
    const int d = threadIdx.x;
    const int t0 = c * 32;
    __shared__ __align__(16) float ft[64][17];
    __shared__ __align__(16) float ht[64][17];
    const float k = tensions[m * 64 + d] / masses[m];
    const float gain = gains[m];
    const float mic = mics[m * 64 + d];
    const float hd = home[d];

    float pos = w[(size_t)blk * 128 + d];
    float vel = w[(size_t)blk * 128 + 64 + d];

    #pragma unroll
    for (int phase = 0; phase < 2; ++phase) {
        const int t0p = t0 + phase * 16;
        for (int i = d; i < 256; i += 64) {
            const int dd = i >> 2, q = (i & 3) * 4;
            const size_t off = ((size_t)bm * 64 + dd) * 2048 + t0p + q;
            *(float4*)&ft[dd][q] = *(const float4*)(forces + off);
            *(float4*)&ht[dd][q] = *(const float4*)(hmod + off);
        }
        __syncthreads();
        #pragma unroll
        for (int ts = 0; ts < 16; ++ts) {
            const float f = ft[d][ts];
            const float h = hd + ht[d][ts];
            const float dir = h - pos;
            const float acc = f + k * dir;
            vel = (vel + acc) * DAMP;
            pos = pos + vel;
            ft[d][ts] = dir;                        // disp tile (in place)
            const float x = vel * gain;
            const float e = __expf(2.f * x);
            ht[d][ts] = (1.f - 2.f / (e + 1.f)) * mic;   // prod tile (in place)
        }
        __syncthreads();
        for (int i = d; i < 256; i += 64) {
            const int dd = i >> 2, q = (i & 3) * 4;
            const size_t off = ((size_t)bm * 64 + dd) * 2048 + t0p + q;
            *(float4*)(disp + off) = *(float4*)&ft[dd][q];
        }
        {
            const int ts = d & 15, part = d >> 4;
            float s = 0.f;
            #pragma unroll
            for (int j = 0; j < 16; ++j) s += ht[16 * part + j][ts];
            s += __shfl_xor(s, 16);
            s += __shfl_xor(s, 32);
            if (d < 16) rec[(size_t)bm * 2048 + t0p + d] = s;
        }
        __syncthreads();
    }
}

// ---------------------------------------------------------------------------
// K2: mixture (fp32 acc -> bf16). [unchanged]
// ---------------------------------------------------------------------------
__global__ __launch_bounds__(256) void mix_kernel(const float* __restrict__ disp,
                                                  const float* __restrict__ tofm,
                                                  unsigned short* __restrict__ mixture) {
    __shared__ __align__(16) float tf[64][16];
    const int tid = threadIdx.x;
    for (int i = tid; i < 1024; i += 256) tf[i >> 4][i & 15] = tofm[i];
    __syncthreads();
    const int bm = blockIdx.y;
    const int t = blockIdx.x * 256 + tid;
    float acc[16];
    #pragma unroll
    for (int f = 0; f < 16; ++f) acc[f] = 0.f;
    for (int d = 0; d < 64; ++d) {
        const float v = disp[((size_t)bm * 64 + d) * 2048 + t];
        const float4* r4 = (const float4*)tf[d];
        const float4 a4 = r4[0], b4 = r4[1], c4 = r4[2], d4 = r4[3];
        acc[0]  += v * a4.x; acc[1]  += v * a4.y; acc[2]  += v * a4.z; acc[3]  += v * a4.w;
        acc[4]  += v * b4.x; acc[5]  += v * b4.y; acc[6]  += v * b4.z; acc[7]  += v * b4.w;
        acc[8]  += v * c4.x; acc[9]  += v * c4.y; acc[10] += v * c4.z; acc[11] += v * c4.w;
        acc[12] += v * d4.x; acc[13] += v * d4.y; acc[14] += v * d4.z; acc[15] += v * d4.w;
    }
    #pragma unroll
    for (int f = 0; f < 16; ++f)
        mixture[((size_t)bm * 16 + f) * 2048 + t] = f2bf(acc[f]);
}

// ---------------------------------------------------------------------------
// K3 (MFMA): fft_resample. [unchanged r7]
// ---------------------------------------------------------------------------
#define DR_STRIDE 4112u
#define W_STRIDE  5136u
#define W_OFF     65792u
#define RS_SMEM   106880u

__global__ __launch_bounds__(256) void resample_kernel(const float* __restrict__ rec,
                                                       const unsigned short* __restrict__ dirrev,
                                                       float* __restrict__ up) {
    const int bm = blockIdx.x;
    const int Q0 = blockIdx.y * 512;
    const int tid = threadIdx.x;
    __shared__ __align__(16) unsigned char smem[RS_SMEM];

    for (int i = tid; i < 4096; i += 256) {
        const int p = i >> 8, c16 = i & 255;
        *(uint4*)(smem + (unsigned)p * DR_STRIDE + 16u * c16) = ((const uint4*)dirrev)[i];
    }
    for (int x = tid; x < 2560; x += 256) {
        const int g = (Q0 + x + 1) & 2047;
        const unsigned short bv = f2bf(rec[(size_t)bm * 2048 + g]);
        #pragma unroll
        for (int sg = 0; sg < 8; ++sg) {
            const int y = x - sg;
            if (y >= 0) *(unsigned short*)(smem + W_OFF + sg * W_STRIDE + 2 * y) = bv;
        }
    }
    __syncthreads();

    const int lane = tid & 63;
    const int wv = tid >> 6;
    const int i15 = lane & 15;
    const int g4 = lane >> 4;

    f32x4 acc[8];
    #pragma unroll
    for (int i = 0; i < 8; ++i) acc[i] = (f32x4){0.f, 0.f, 0.f, 0.f};

    const unsigned abase = (unsigned)i15 * DR_STRIDE + 16u * g4;
    const unsigned bbase = W_OFF + (unsigned)(i15 & 7) * W_STRIDE + 16u * (i15 >> 3) + 16u * g4;

    for (int kkb = 0; kkb < 8; ++kkb) {
        bf16x8 afr[8];
        #pragma unroll
        for (int kj = 0; kj < 8; ++kj)
            afr[kj] = *(const bf16x8*)(smem + abase + 64u * (kkb * 8 + kj));
        #pragma unroll
        for (int qtl = 0; qtl < 8; ++qtl) {
            const int qt = wv * 8 + qtl;
            const unsigned bb = bbase + 32u * qt;
            #pragma unroll
            for (int kj = 0; kj < 8; ++kj) {
                const bf16x8 bfr = *(const bf16x8*)(smem + bb + 64u * (kkb * 8 + kj));
                acc[qtl] = __builtin_amdgcn_mfma_f32_16x16x32_bf16(afr[kj], bfr, acc[qtl], 0, 0, 0);
            }
        }
    }

    #pragma unroll
    for (int qtl = 0; qtl < 8; ++qtl) {
        const int qt = wv * 8 + qtl;
        const int q = Q0 + 16 * qt + i15;
        const int sbase = 16 * q + 4 * g4;
        const unsigned jb = (unsigned)bm * 32768u + (unsigned)sbase;
        float4 o;
        o.x = fabsf(acc[qtl][0] * (1.f / 8192.f)) * noise_at(jb);
        o.y = fabsf(acc[qtl][1] * (1.f / 8192.f)) * noise_at(jb + 1u);
        o.z = fabsf(acc[qtl][2] * (1.f / 8192.f)) * noise_at(jb + 2u);
        o.w = fabsf(acc[qtl][3] * (1.f / 8192.f)) * noise_at(jb + 3u);
        *(float4*)(up + (size_t)bm * 32768 + sbase) = o;
    }
}

// ---------------------------------------------------------------------------
// K4 (MFMA): hf — lean FIR-only kernel, scalar 8-copy staging. [r10-verified]
// grid (32 s-tiles of 1024, 64 bm), 256 threads.
// ---------------------------------------------------------------------------
#define W_STR2   3088u            // 1544 bf16, padded (1536 used)
#define MX_OFF   24704u           // 8*3088
#define HF_SMEM  26880u           // + 16*68*2

__global__ __launch_bounds__(256) void hf_kernel(const float* __restrict__ up,
                                                 const unsigned short* __restrict__ fnrev,
                                                 const unsigned short* __restrict__ mixture,
                                                 float* __restrict__ hf) {
    const int tile = blockIdx.x;     // 0..31
    const int bm = blockIdx.y;       // 0..63
    const int b = bm >> 5;
    const int S0 = tile * 1024;
    const int tbase = tile * 64 - 1;
    const int tid = threadIdx.x;

    __shared__ __align__(16) unsigned char smem[HF_SMEM];
    unsigned short* mixl = (unsigned short*)(smem + MX_OFF);

    // stage 8 shifted copies: W[x] = up[S0-511+x], x in [0,1536)
    for (int x = tid; x < 1536; x += 256) {
        const int gidx = S0 - 511 + x;
        const float u = (gidx >= 0 && gidx < 32768) ? up[(size_t)bm * 32768 + gidx] : 0.f;
        const unsigned short v = f2bf(u);
        #pragma unroll
        for (int sg = 0; sg < 8; ++sg) {
            const int y = x - sg;
            if (y >= 0) *(unsigned short*)(smem + sg * W_STR2 + 2 * y) = v;
        }
    }
    // stage mixl window (bf16): 16 f x 66 t
    for (int i = tid; i < 16 * 66; i += 256) {
        const int f = i / 66, tt = i - f * 66;
        const int t = tbase + tt;
        mixl[f * 68 + tt] = (t >= 0 && t < 2048)
            ? mixture[((size_t)bm * 16 + f) * 2048 + t] : (unsigned short)0;
    }
    // A-fragments from fnrev (L2-cached, 16B aligned loads)
    const int lane = tid & 63;
    const int i15 = lane & 15;
    const int g4 = lane >> 4;
    const int wv = tid >> 6;
    bf16x8 afr[16];
    #pragma unroll
    for (int kk = 0; kk < 16; ++kk)
        afr[kk] = *(const bf16x8*)(fnrev + (size_t)(b * 16 + i15) * 512 + 32 * kk + 8 * g4);
    __syncthreads();

    for (int rr = 0; rr < 4; ++rr) {
        const int rho = wv * 4 + rr;            // s residue 0..15
        const int sig = rho & 7;
        const unsigned baseR = (unsigned)sig * W_STR2 + 2u * (rho - sig)
                             + 32u * i15 + 16u * g4;
        #pragma unroll
        for (int g = 0; g < 4; ++g) {
            f32x4 acc = {0.f, 0.f, 0.f, 0.f};
            const unsigned tb = baseR + 512u * g;
            #pragma unroll
            for (int kk = 0; kk < 16; ++kk) {
                const bf16x8 bfr = *(const bf16x8*)(smem + tb + 64u * kk);
                acc = __builtin_amdgcn_mfma_f32_16x16x32_bf16(afr[kk], bfr, acc, 0, 0, 0);
            }
            const int s = S0 + 256 * g + rho + 16 * i15;
            float posf = ((float)s + 0.5f) * 0.0625f - 0.5f;
            posf = fminf(fmaxf(posf, 0.f), 2047.f);
            const int i0 = (int)posf;
            const float wg = posf - (float)i0;
            const int i1 = min(i0 + 1, 2047);
            const int t0 = i0 - tbase, t1 = i1 - tbase;
            float part = 0.f;
            #pragma unroll
            for (int r = 0; r < 4; ++r) {
                const int f = 4 * g4 + r;
                const float mv = bf2f(mixl[f * 68 + t0]) * (1.f - wg)
                               + bf2f(mixl[f * 68 + t1]) * wg;
                part += mv * acc[r];
            }
            part += __shfl_xor(part, 16);
            part += __shfl_xor(part, 32);
            if (g4 == 0) {
                const int e = 511 + 256 * g + rho + 16 * i15;   // copy-0 element
                const float upv = bf2f(*(const unsigned short*)(smem + 2 * e));
                hf[(size_t)bm * 32768 + s] = part + upv;
            }
        }
    }
}

// ---------------------------------------------------------------------------
// Launch
// ---------------------------------------------------------------------------
extern "C" void kernel_launch(void* const* d_in, const int* in_sizes, int n_in,
                              void* d_out, int out_size, void* d_ws, size_t ws_size,
                              hipStream_t stream) {
    const float* forces   = (const float*)d_in[0];
    const float* hmod     = (const float*)d_in[1];
    const float* filters  = (const float*)d_in[2];
    const float* home     = (const float*)d_in[3];
    const float* masses   = (const float*)d_in[4];
    const float* tensions = (const float*)d_in[5];
    const float* gains    = (const float*)d_in[6];
    const float* mics     = (const float*)d_in[7];
    const float* tofm     = (const float*)d_in[8];

    float* out  = (float*)d_out;
    float* rec  = out;                  // 131072
    float* disp = out + 131072;         // 8388608
    float* hf   = out + 8519680;        // 2097152

    float* up               = (float*)d_ws;                             // 2097152 f32
    unsigned short* mixture = (unsigned short*)((float*)d_ws + 2097152);// 2097152 bf16
    unsigned short* dirrev  = (unsigned short*)((float*)d_ws + 3145728);// 32768 bf16
    float* w                = (float*)d_ws + 3162112;                   // 524288 f32
    unsigned short* fnrev   = (unsigned short*)((float*)d_ws + 3686400);// 16384 bf16
    // total ws use ~14.8 MB

    tables_kernel<<<160, 256, 0, stream>>>(filters, dirrev, fnrev);
    sim_pass1<<<4096, 64, 0, stream>>>(forces, hmod, home, masses, tensions, w);
    sim_scan<<<64, 64, 0, stream>>>(masses, tensions, w);
    sim_pass2<<<4096, 64, 0, stream>>>(forces, hmod, home, masses, tensions, gains, mics, w, disp, rec);
    mix_kernel<<<dim3(8, 64), 256, 0, stream>>>(disp, tofm, mixture);
    resample_kernel<<<dim3(64, 4), 256, 0, stream>>>(rec, dirrev, up);
    hf_kernel<<<dim3(32, 64), 256, 0, stream>>>(up, fnrev, mixture, hf);
}

// Round 14
// 122.091 us; speedup vs baseline: 1.8608x; 1.0580x over previous
//
#include <hip/hip_runtime.h>
#include <cstdint>
#include <cstddef>

// Problem constants (B=2, M=32, D=64, T=2048, F=16, L=512, S=32768)
#define DAMP 0.9998f

typedef __attribute__((ext_vector_type(8))) short bf16x8;
typedef __attribute__((ext_vector_type(4))) unsigned short u16x4;
typedef __attribute__((ext_vector_type(4))) float f32x4;

__device__ __forceinline__ unsigned short f2bf(float x) {
    unsigned u = __float_as_uint(x);
    unsigned r = (u + 0x7FFFu + ((u >> 16) & 1u)) >> 16;   // RNE
    return (unsigned short)r;
}
__device__ __forceinline__ float bf2f(unsigned short v) {
    return __uint_as_float((unsigned)v << 16);
}

// ---------------------------------------------------------------------------
// threefry2x32, JAX partitionable mode. key=(0,1); counter (0, j); o0^o1.
// [verified r4]
// ---------------------------------------------------------------------------
__device__ __forceinline__ void threefry_0j(unsigned j, unsigned& o0, unsigned& o1) {
    unsigned x0 = 0u;
    unsigned x1 = j + 1u;
    const unsigned ks2 = 0x1BD11BDBu;
#define TFR(r) { x0 += x1; x1 = (x1 << (r)) | (x1 >> (32 - (r))); x1 ^= x0; }
    TFR(13) TFR(15) TFR(26) TFR(6)
    x0 += 1u;   x1 += ks2 + 1u;
    TFR(17) TFR(29) TFR(16) TFR(24)
    x0 += ks2;  x1 += 0u + 2u;
    TFR(13) TFR(15) TFR(26) TFR(6)
    /*x0+=0*/   x1 += 1u + 3u;
    TFR(17) TFR(29) TFR(16) TFR(24)
    x0 += 1u;   x1 += ks2 + 4u;
    TFR(13) TFR(15) TFR(26) TFR(6)
    x0 += ks2;  x1 += 0u + 5u;
#undef TFR
    o0 = x0; o1 = x1;
}

__device__ __forceinline__ float noise_at(unsigned j) {
    unsigned o0, o1;
    threefry_0j(j, o0, o1);
    unsigned bits = o0 ^ o1;
    float u = __uint_as_float((bits >> 9) | 0x3F800000u) - 1.0f;
    return fmaxf(-1.0f, u * 2.0f - 1.0f);
}

// Dir(u) = sin(2049*pi*u/32768)/sin(pi*u/32768), Dir(0)=2049, period 32768.
__device__ __forceinline__ float dir_val(unsigned u) {
    if (u == 0u) return 2049.f;
    const float PIO = 9.58737992e-05f;
    unsigned y = (2049u * u) & 65535u;
    float sgn = 1.f;
    if (y >= 32768u) { y -= 32768u; sgn = -1.f; }
    unsigned yy = (y > 16384u) ? (32768u - y) : y;
    float sy = sgn * sinf((float)yy * PIO);
    unsigned uu = (u > 16384u) ? (32768u - u) : u;
    float su = sinf((float)uu * PIO);
    return sy / su;
}

// ---------------------------------------------------------------------------
// K1a: sim pass 1 + tables. Blocks [0,4096): 32-step chunk local affine
// constant w_c (r10-verified). Blocks [4096,4608): DirRev table. Blocks
// [4608,4640): normalized reversed filters. Table blocks take a separate
// branch (no shared __syncthreads with pass1 path).
// ---------------------------------------------------------------------------
__global__ __launch_bounds__(64) void sim_pass1(const float* __restrict__ forces,
                                                const float* __restrict__ hmod,
                                                const float* __restrict__ home,
                                                const float* __restrict__ masses,
                                                const float* __restrict__ tensions,
                                                float* __restrict__ w,
                                                const float* __restrict__ filters,
                                                unsigned short* __restrict__ dirrev,
                                                unsigned short* __restrict__ fnrev) {
    const int blk = blockIdx.x;
    const int d = threadIdx.x;
    if (blk >= 4608) {               // fnrev: 32 blocks x 64 threads
        const int row = blk - 4608;
        const float* src = filters + (size_t)row * 512;
        float s = 0.f;
        for (int i = d; i < 512; i += 64) { const float v = src[i]; s += v * v; }
        #pragma unroll
        for (int off = 32; off; off >>= 1) s += __shfl_xor(s, off);
        const float scale = 1.f / (sqrtf(s) + 1e-8f);
        for (int i = d; i < 512; i += 64)
            fnrev[(size_t)row * 512 + i] = f2bf(src[511 - i] * scale);
        return;
    }
    if (blk >= 4096) {               // dirrev: 512 blocks x 64 threads
        const unsigned i = (unsigned)(blk - 4096) * 64u + (unsigned)d;
        const unsigned p = i >> 11, k = i & 2047u;
        dirrev[i] = f2bf(dir_val(16u * (2047u - k) + p));
        return;
    }
    const int bm = blk >> 6, c = blk & 63;
    const int m = bm & 31;
    const int t0 = c * 32;
    __shared__ float kv[64];
    __shared__ float hv[64];
    __shared__ __align__(16) float gt[64][33];
    kv[d] = tensions[m * 64 + d] / masses[m];
    hv[d] = home[d];
    __syncthreads();
    for (int i = d; i < 512; i += 64) {
        const int dd = i >> 3, q = (i & 7) * 4;
        const size_t off = ((size_t)bm * 64 + dd) * 2048 + t0 + q;
        const float4 fv = *(const float4*)(forces + off);
        const float4 hm = *(const float4*)(hmod + off);
        const float kk = kv[dd], hh = hv[dd];
        float4 g;
        g.x = fmaf(kk, hh + hm.x, fv.x);
        g.y = fmaf(kk, hh + hm.y, fv.y);
        g.z = fmaf(kk, hh + hm.z, fv.z);
        g.w = fmaf(kk, hh + hm.w, fv.w);
        *(float4*)&gt[dd][q] = g;
    }
    __syncthreads();
    const float k = kv[d];
    float pos = 0.f, vel = 0.f;
    #pragma unroll 8
    for (int ts = 0; ts < 32; ++ts) {
        const float acc = fmaf(-k, pos, gt[d][ts]);
        vel = (vel + acc) * DAMP;
        pos = pos + vel;
    }
    float* wrow = w + (size_t)blk * 128;
    wrow[d] = pos; wrow[64 + d] = vel;
}

// ---------------------------------------------------------------------------
// K1b: sim scan — fp64 A^32, serial scan over 64 chunks per (bm,d).
// IN PLACE: reads w[c], overwrites the slot with the chunk-ENTRY state.
// grid 64 (bm), 64 threads (d).  [r10-verified]
// ---------------------------------------------------------------------------
__global__ __launch_bounds__(64) void sim_scan(const float* __restrict__ masses,
                                               const float* __restrict__ tensions,
                                               float* __restrict__ w) {
    const int bm = blockIdx.x;
    const int m = bm & 31;
    const int d = threadIdx.x;
    const double kd = (double)(tensions[m * 64 + d] / masses[m]);
    const double cd = (double)DAMP;
    double Ma = 1.0 - cd * kd, Mb = cd, Mc = -cd * kd, Md = cd;
    #pragma unroll
    for (int it = 0; it < 5; ++it) {             // A^(2^5) = A^32
        const double na = Ma * Ma + Mb * Mc;
        const double nb = Ma * Mb + Mb * Md;
        const double nc = Mc * Ma + Md * Mc;
        const double nd = Mc * Mb + Md * Md;
        Ma = na; Mb = nb; Mc = nc; Md = nd;
    }
    double pos = 0.0, vel = 0.0;
    float* wb = w + (size_t)bm * 64 * 128;
    for (int c = 0; c < 64; ++c) {
        float* row = wb + c * 128;
        const double wp = (double)row[d];
        const double wv = (double)row[64 + d];
        row[d] = (float)pos;                     // entry state of chunk c
        row[64 + d] = (float)vel;
        const double np = Ma * pos + Mb * vel + wp;
        const double nv = Mc * pos + Md * vel + wv;
        pos = np; vel = nv;
    }
}

// ---------------------------------------------------------------------------
// K1c: sim pass 2 — 32-step emit from precomputed entry state, two 16-ts
// quarter stages. LDS 8.9 KB.  [r10-verified]
// ---------------------------------------------------------------------------
__global__ __launch_bounds__(64) void sim_pass2(const float* __restrict__ forces,
                                                const float* __restrict__ hmod,
                                                const float* __restrict__ home,
                                                const float* __restrict__ masses,
                                                const float* __restrict__ tensions,
                                                const float* __restrict__ gains,
                                                const float* __restrict__ mics,
                                                const float* __restrict__ w,
                                                float* __restrict__ disp,
                                                float* __restrict__ rec) {
    const int blk = blockIdx.x;
    const int bm = blk >> 6, c = blk & 63;
    const int m = bm & 31;
    const int d = threadIdx.x;
    const int t0 = c * 32;
    __shared__ __align__(16) float ft[64][17];
    __shared__ __align__(16) float ht[64][17];
    const float k = tensions[m * 64 + d] / masses[m];
    const float gain = gains[m];
    const float mic = mics[m * 64 + d];
    const float hd = home[d];

    float pos = w[(size_t)blk * 128 + d];
    float vel = w[(size_t)blk * 128 + 64 + d];

    #pragma unroll
    for (int phase = 0; phase < 2; ++phase) {
        const int t0p = t0 + phase * 16;
        for (int i = d; i < 256; i += 64) {
            const int dd = i >> 2, q = (i & 3) * 4;
            const size_t off = ((size_t)bm * 64 + dd) * 2048 + t0p + q;
            *(float4*)&ft[dd][q] = *(const float4*)(forces + off);
            *(float4*)&ht[dd][q] = *(const float4*)(hmod + off);
        }
        __syncthreads();
        #pragma unroll
        for (int ts = 0; ts < 16; ++ts) {
            const float f = ft[d][ts];
            const float h = hd + ht[d][ts];
            const float dir = h - pos;
            const float acc = f + k * dir;
            vel = (vel + acc) * DAMP;
            pos = pos + vel;
            ft[d][ts] = dir;                        // disp tile (in place)
            const float x = vel * gain;
            const float e = __expf(2.f * x);
            ht[d][ts] = (1.f - 2.f / (e + 1.f)) * mic;   // prod tile (in place)
        }
        __syncthreads();
        for (int i = d; i < 256; i += 64) {
            const int dd = i >> 2, q = (i & 3) * 4;
            const size_t off = ((size_t)bm * 64 + dd) * 2048 + t0p + q;
            *(float4*)(disp + off) = *(float4*)&ft[dd][q];
        }
        {
            const int ts = d & 15, part = d >> 4;
            float s = 0.f;
            #pragma unroll
            for (int j = 0; j < 16; ++j) s += ht[16 * part + j][ts];
            s += __shfl_xor(s, 16);
            s += __shfl_xor(s, 32);
            if (d < 16) rec[(size_t)bm * 2048 + t0p + d] = s;
        }
        __syncthreads();
    }
}

// ---------------------------------------------------------------------------
// K2: mixture (fp32 acc -> bf16). [unchanged]
// ---------------------------------------------------------------------------
__global__ __launch_bounds__(256) void mix_kernel(const float* __restrict__ disp,
                                                  const float* __restrict__ tofm,
                                                  unsigned short* __restrict__ mixture) {
    __shared__ __align__(16) float tf[64][16];
    const int tid = threadIdx.x;
    for (int i = tid; i < 1024; i += 256) tf[i >> 4][i & 15] = tofm[i];
    __syncthreads();
    const int bm = blockIdx.y;
    const int t = blockIdx.x * 256 + tid;
    float acc[16];
    #pragma unroll
    for (int f = 0; f < 16; ++f) acc[f] = 0.f;
    for (int d = 0; d < 64; ++d) {
        const float v = disp[((size_t)bm * 64 + d) * 2048 + t];
        const float4* r4 = (const float4*)tf[d];
        const float4 a4 = r4[0], b4 = r4[1], c4 = r4[2], d4 = r4[3];
        acc[0]  += v * a4.x; acc[1]  += v * a4.y; acc[2]  += v * a4.z; acc[3]  += v * a4.w;
        acc[4]  += v * b4.x; acc[5]  += v * b4.y; acc[6]  += v * b4.z; acc[7]  += v * b4.w;
        acc[8]  += v * c4.x; acc[9]  += v * c4.y; acc[10] += v * c4.z; acc[11] += v * c4.w;
        acc[12] += v * d4.x; acc[13] += v * d4.y; acc[14] += v * d4.z; acc[15] += v * d4.w;
    }
    #pragma unroll
    for (int f = 0; f < 16; ++f)
        mixture[((size_t)bm * 16 + f) * 2048 + t] = f2bf(acc[f]);
}

// ---------------------------------------------------------------------------
// K3 (MFMA): fft_resample — DirRev staged in 2 K-chunks (LDS 74.1 KB ->
// 2 blocks/CU); epilogue writes up as bf16 (hf consumes only bf16(up)).
// Fragment/bank math identical to r7-verified kernel; B-reads use global
// K offsets (+2048B per chunk), A-reads chunk-local.
// ---------------------------------------------------------------------------
#define DR_STRIDE 2064u           // 1024 bf16 + 16B pad; == 16 mod 128
#define W_STRIDE  5136u
#define W_OFF     33024u          // 16*2064
#define RS_SMEM   74112u          // + 8*5136

__global__ __launch_bounds__(256) void resample_kernel(const float* __restrict__ rec,
                                                       const unsigned short* __restrict__ dirrev,
                                                       unsigned short* __restrict__ upb) {
    const int bm = blockIdx.x;
    const int Q0 = blockIdx.y * 512;
    const int tid = threadIdx.x;
    __shared__ __align__(16) unsigned char smem[RS_SMEM];

    // stage window copies once: W[x] = rec[(Q0+x+1) & 2047]
    for (int x = tid; x < 2560; x += 256) {
        const int g = (Q0 + x + 1) & 2047;
        const unsigned short bv = f2bf(rec[(size_t)bm * 2048 + g]);
        #pragma unroll
        for (int sg = 0; sg < 8; ++sg) {
            const int y = x - sg;
            if (y >= 0) *(unsigned short*)(smem + W_OFF + sg * W_STRIDE + 2 * y) = bv;
        }
    }

    const int lane = tid & 63;
    const int wv = tid >> 6;
    const int i15 = lane & 15;
    const int g4 = lane >> 4;

    f32x4 acc[8];
    #pragma unroll
    for (int i = 0; i < 8; ++i) acc[i] = (f32x4){0.f, 0.f, 0.f, 0.f};

    const unsigned abase = (unsigned)i15 * DR_STRIDE + 16u * g4;
    const unsigned bbase = W_OFF + (unsigned)(i15 & 7) * W_STRIDE + 16u * (i15 >> 3) + 16u * g4;

    for (int kc = 0; kc < 2; ++kc) {
        if (kc) __syncthreads();          // all waves done reading prev chunk
        // stage DirRev chunk: rows p, k' in [0,1024): dirrev[p*2048 + kc*1024 + k']
        for (int i = tid; i < 2048; i += 256) {
            const int p = i >> 7, c16 = i & 127;
            *(uint4*)(smem + (unsigned)p * DR_STRIDE + 16u * c16) =
                *(const uint4*)(dirrev + (size_t)p * 2048 + kc * 1024 + 8 * c16);
        }
        __syncthreads();

        for (int kkb = 0; kkb < 4; ++kkb) {
            bf16x8 afr[8];
            #pragma unroll
            for (int kj = 0; kj < 8; ++kj)
                afr[kj] = *(const bf16x8*)(smem + abase + 64u * (kkb * 8 + kj));
            #pragma unroll
            for (int qtl = 0; qtl < 8; ++qtl) {
                const int qt = wv * 8 + qtl;
                const unsigned bb = bbase + 32u * qt + 2048u * kc;
                #pragma unroll
                for (int kj = 0; kj < 8; ++kj) {
                    const bf16x8 bfr = *(const bf16x8*)(smem + bb + 64u * (kkb * 8 + kj));
                    acc[qtl] = __builtin_amdgcn_mfma_f32_16x16x32_bf16(afr[kj], bfr, acc[qtl], 0, 0, 0);
                }
            }
        }
    }

    #pragma unroll
    for (int qtl = 0; qtl < 8; ++qtl) {
        const int qt = wv * 8 + qtl;
        const int q = Q0 + 16 * qt + i15;
        const int sbase = 16 * q + 4 * g4;
        const unsigned jb = (unsigned)bm * 32768u + (unsigned)sbase;
        u16x4 o;
        o[0] = f2bf(fabsf(acc[qtl][0] * (1.f / 8192.f)) * noise_at(jb));
        o[1] = f2bf(fabsf(acc[qtl][1] * (1.f / 8192.f)) * noise_at(jb + 1u));
        o[2] = f2bf(fabsf(acc[qtl][2] * (1.f / 8192.f)) * noise_at(jb + 2u));
        o[3] = f2bf(fabsf(acc[qtl][3] * (1.f / 8192.f)) * noise_at(jb + 3u));
        *(u16x4*)(upb + (size_t)bm * 32768 + sbase) = o;
    }
}

// ---------------------------------------------------------------------------
// K4 (MFMA): hf — lean FIR-only kernel, scalar 8-copy staging from bf16 up.
// grid (32 s-tiles of 1024, 64 bm), 256 threads.  [r10-verified structure]
// ---------------------------------------------------------------------------
#define W_STR2   3088u            // 1544 bf16, padded (1536 used)
#define MX_OFF   24704u           // 8*3088
#define HF_SMEM  26880u           // + 16*68*2

__global__ __launch_bounds__(256) void hf_kernel(const unsigned short* __restrict__ upb,
                                                 const unsigned short* __restrict__ fnrev,
                                                 const unsigned short* __restrict__ mixture,
                                                 float* __restrict__ hf) {
    const int tile = blockIdx.x;     // 0..31
    const int bm = blockIdx.y;       // 0..63
    const int b = bm >> 5;
    const int S0 = tile * 1024;
    const int tbase = tile * 64 - 1;
    const int tid = threadIdx.x;

    __shared__ __align__(16) unsigned char smem[HF_SMEM];
    unsigned short* mixl = (unsigned short*)(smem + MX_OFF);

    // stage 8 shifted copies: W[x] = upb[S0-511+x], x in [0,1536)
    for (int x = tid; x < 1536; x += 256) {
        const int gidx = S0 - 511 + x;
        const unsigned short v = (gidx >= 0) ? upb[(size_t)bm * 32768 + gidx]
                                             : (unsigned short)0;
        #pragma unroll
        for (int sg = 0; sg < 8; ++sg) {
            const int y = x - sg;
            if (y >= 0) *(unsigned short*)(smem + sg * W_STR2 + 2 * y) = v;
        }
    }
    // stage mixl window (bf16): 16 f x 66 t
    for (int i = tid; i < 16 * 66; i += 256) {
        const int f = i / 66, tt = i - f * 66;
        const int t = tbase + tt;
        mixl[f * 68 + tt] = (t >= 0 && t < 2048)
            ? mixture[((size_t)bm * 16 + f) * 2048 + t] : (unsigned short)0;
    }
    // A-fragments from fnrev (L2-cached, 16B aligned loads)
    const int lane = tid & 63;
    const int i15 = lane & 15;
    const int g4 = lane >> 4;
    const int wv = tid >> 6;
    bf16x8 afr[16];
    #pragma unroll
    for (int kk = 0; kk < 16; ++kk)
        afr[kk] = *(const bf16x8*)(fnrev + (size_t)(b * 16 + i15) * 512 + 32 * kk + 8 * g4);
    __syncthreads();

    for (int rr = 0; rr < 4; ++rr) {
        const int rho = wv * 4 + rr;            // s residue 0..15
        const int sig = rho & 7;
        const unsigned baseR = (unsigned)sig * W_STR2 + 2u * (rho - sig)
                             + 32u * i15 + 16u * g4;
        #pragma unroll
        for (int g = 0; g < 4; ++g) {
            f32x4 acc = {0.f, 0.f, 0.f, 0.f};
            const unsigned tb = baseR + 512u * g;
            #pragma unroll
            for (int kk = 0; kk < 16; ++kk) {
                const bf16x8 bfr = *(const bf16x8*)(smem + tb + 64u * kk);
                acc = __builtin_amdgcn_mfma_f32_16x16x32_bf16(afr[kk], bfr, acc, 0, 0, 0);
            }
            const int s = S0 + 256 * g + rho + 16 * i15;
            float posf = ((float)s + 0.5f) * 0.0625f - 0.5f;
            posf = fminf(fmaxf(posf, 0.f), 2047.f);
            const int i0 = (int)posf;
            const float wg = posf - (float)i0;
            const int i1 = min(i0 + 1, 2047);
            const int t0 = i0 - tbase, t1 = i1 - tbase;
            float part = 0.f;
            #pragma unroll
            for (int r = 0; r < 4; ++r) {
                const int f = 4 * g4 + r;
                const float mv = bf2f(mixl[f * 68 + t0]) * (1.f - wg)
                               + bf2f(mixl[f * 68 + t1]) * wg;
                part += mv * acc[r];
            }
            part += __shfl_xor(part, 16);
            part += __shfl_xor(part, 32);
            if (g4 == 0) {
                const int e = 511 + 256 * g + rho + 16 * i15;   // copy-0 element
                const float upv = bf2f(*(const unsigned short*)(smem + 2 * e));
                hf[(size_t)bm * 32768 + s] = part + upv;
            }
        }
    }
}

// ---------------------------------------------------------------------------
// Launch
// ---------------------------------------------------------------------------
extern "C" void kernel_launch(void* const* d_in, const int* in_sizes, int n_in,
                              void* d_out, int out_size, void* d_ws, size_t ws_size,
                              hipStream_t stream) {
    const float* forces   = (const float*)d_in[0];
    const float* hmod     = (const float*)d_in[1];
    const float* filters  = (const float*)d_in[2];
    const float* home     = (const float*)d_in[3];
    const float* masses   = (const float*)d_in[4];
    const float* tensions = (const float*)d_in[5];
    const float* gains    = (const float*)d_in[6];
    const float* mics     = (const float*)d_in[7];
    const float* tofm     = (const float*)d_in[8];

    float* out  = (float*)d_out;
    float* rec  = out;                  // 131072
    float* disp = out + 131072;         // 8388608
    float* hf   = out + 8519680;        // 2097152

    unsigned short* upb     = (unsigned short*)d_ws;                    // 2097152 bf16 (4MB)
    unsigned short* mixture = (unsigned short*)((float*)d_ws + 1048576);// 2097152 bf16 (4MB)
    unsigned short* dirrev  = (unsigned short*)((float*)d_ws + 2097152);// 32768 bf16
    float* w                = (float*)d_ws + 2113536;                   // 524288 f32 (2MB)
    unsigned short* fnrev   = (unsigned short*)((float*)d_ws + 2637824);// 16384 bf16
    // total ws use ~10.2 MB

    sim_pass1<<<4640, 64, 0, stream>>>(forces, hmod, home, masses, tensions, w,
                                       filters, dirrev, fnrev);
    sim_scan<<<64, 64, 0, stream>>>(masses, tensions, w);
    sim_pass2<<<4096, 64, 0, stream>>>(forces, hmod, home, masses, tensions, gains, mics, w, disp, rec);
    mix_kernel<<<dim3(8, 64), 256, 0, stream>>>(disp, tofm, mixture);
    resample_kernel<<<dim3(64, 4), 256, 0, stream>>>(rec, dirrev, upb);
    hf_kernel<<<dim3(32, 64), 256, 0, stream>>>(upb, fnrev, mixture, hf);
}

// Round 15
// 120.170 us; speedup vs baseline: 1.8905x; 1.0160x over previous
//
#include <hip/hip_runtime.h>
#include <cstdint>
#include <cstddef>

// Problem constants (B=2, M=32, D=64, T=2048, F=16, L=512, S=32768)
#define DAMP 0.9998f

typedef __attribute__((ext_vector_type(8))) short bf16x8;
typedef __attribute__((ext_vector_type(4))) unsigned short u16x4;
typedef __attribute__((ext_vector_type(4))) float f32x4;

__device__ __forceinline__ unsigned short f2bf(float x) {
    unsigned u = __float_as_uint(x);
    unsigned r = (u + 0x7FFFu + ((u >> 16) & 1u)) >> 16;   // RNE
    return (unsigned short)r;
}
__device__ __forceinline__ float bf2f(unsigned short v) {
    return __uint_as_float((unsigned)v << 16);
}

// ---------------------------------------------------------------------------
// threefry2x32, JAX partitionable mode. key=(0,1); counter (0, j); o0^o1.
// [verified r4]
// ---------------------------------------------------------------------------
__device__ __forceinline__ void threefry_0j(unsigned j, unsigned& o0, unsigned& o1) {
    unsigned x0 = 0u;
    unsigned x1 = j + 1u;
    const unsigned ks2 = 0x1BD11BDBu;
#define TFR(r) { x0 += x1; x1 = (x1 << (r)) | (x1 >> (32 - (r))); x1 ^= x0; }
    TFR(13) TFR(15) TFR(26) TFR(6)
    x0 += 1u;   x1 += ks2 + 1u;
    TFR(17) TFR(29) TFR(16) TFR(24)
    x0 += ks2;  x1 += 0u + 2u;
    TFR(13) TFR(15) TFR(26) TFR(6)
    /*x0+=0*/   x1 += 1u + 3u;
    TFR(17) TFR(29) TFR(16) TFR(24)
    x0 += 1u;   x1 += ks2 + 4u;
    TFR(13) TFR(15) TFR(26) TFR(6)
    x0 += ks2;  x1 += 0u + 5u;
#undef TFR
    o0 = x0; o1 = x1;
}

__device__ __forceinline__ float noise_at(unsigned j) {
    unsigned o0, o1;
    threefry_0j(j, o0, o1);
    unsigned bits = o0 ^ o1;
    float u = __uint_as_float((bits >> 9) | 0x3F800000u) - 1.0f;
    return fmaxf(-1.0f, u * 2.0f - 1.0f);
}

// Dir(u) = sin(2049*pi*u/32768)/sin(pi*u/32768), Dir(0)=2049, period 32768.
__device__ __forceinline__ float dir_val(unsigned u) {
    if (u == 0u) return 2049.f;
    const float PIO = 9.58737992e-05f;
    unsigned y = (2049u * u) & 65535u;
    float sgn = 1.f;
    if (y >= 32768u) { y -= 32768u; sgn = -1.f; }
    unsigned yy = (y > 16384u) ? (32768u - y) : y;
    float sy = sgn * sinf((float)yy * PIO);
    unsigned uu = (u > 16384u) ? (32768u - u) : u;
    float su = sinf((float)uu * PIO);
    return sy / su;
}

// ---------------------------------------------------------------------------
// K1a: sim pass 1 + tables. Blocks [0,4096): 32-step chunk local affine
// constant w_c (r10-verified). Blocks [4096,4608): DirRev table. Blocks
// [4608,4640): normalized reversed filters.
// ---------------------------------------------------------------------------
__global__ __launch_bounds__(64) void sim_pass1(const float* __restrict__ forces,
                                                const float* __restrict__ hmod,
                                                const float* __restrict__ home,
                                                const float* __restrict__ masses,
                                                const float* __restrict__ tensions,
                                                float* __restrict__ w,
                                                const float* __restrict__ filters,
                                                unsigned short* __restrict__ dirrev,
                                                unsigned short* __restrict__ fnrev) {
    const int blk = blockIdx.x;
    const int d = threadIdx.x;
    if (blk >= 4608) {               // fnrev: 32 blocks x 64 threads
        const int row = blk - 4608;
        const float* src = filters + (size_t)row * 512;
        float s = 0.f;
        for (int i = d; i < 512; i += 64) { const float v = src[i]; s += v * v; }
        #pragma unroll
        for (int off = 32; off; off >>= 1) s += __shfl_xor(s, off);
        const float scale = 1.f / (sqrtf(s) + 1e-8f);
        for (int i = d; i < 512; i += 64)
            fnrev[(size_t)row * 512 + i] = f2bf(src[511 - i] * scale);
        return;
    }
    if (blk >= 4096) {               // dirrev: 512 blocks x 64 threads
        const unsigned i = (unsigned)(blk - 4096) * 64u + (unsigned)d;
        const unsigned p = i >> 11, k = i & 2047u;
        dirrev[i] = f2bf(dir_val(16u * (2047u - k) + p));
        return;
    }
    const int bm = blk >> 6, c = blk & 63;
    const int m = bm & 31;
    const int t0 = c * 32;
    __shared__ float kv[64];
    __shared__ float hv[64];
    __shared__ __align__(16) float gt[64][33];
    kv[d] = tensions[m * 64 + d] / masses[m];
    hv[d] = home[d];
    __syncthreads();
    for (int i = d; i < 512; i += 64) {
        const int dd = i >> 3, q = (i & 7) * 4;
        const size_t off = ((size_t)bm * 64 + dd) * 2048 + t0 + q;
        const float4 fv = *(const float4*)(forces + off);
        const float4 hm = *(const float4*)(hmod + off);
        const float kk = kv[dd], hh = hv[dd];
        float4 g;
        g.x = fmaf(kk, hh + hm.x, fv.x);
        g.y = fmaf(kk, hh + hm.y, fv.y);
        g.z = fmaf(kk, hh + hm.z, fv.z);
        g.w = fmaf(kk, hh + hm.w, fv.w);
        *(float4*)&gt[dd][q] = g;
    }
    __syncthreads();
    const float k = kv[d];
    float pos = 0.f, vel = 0.f;
    #pragma unroll 8
    for (int ts = 0; ts < 32; ++ts) {
        const float acc = fmaf(-k, pos, gt[d][ts]);
        vel = (vel + acc) * DAMP;
        pos = pos + vel;
    }
    float* wrow = w + (size_t)blk * 128;
    wrow[d] = pos; wrow[64 + d] = vel;
}

// ---------------------------------------------------------------------------
// K1b: sim scan — fp64 A^32, serial scan over 64 chunks per (bm,d).
// IN PLACE.  grid 64 (bm), 64 threads (d).  [r10-verified]
// ---------------------------------------------------------------------------
__global__ __launch_bounds__(64) void sim_scan(const float* __restrict__ masses,
                                               const float* __restrict__ tensions,
                                               float* __restrict__ w) {
    const int bm = blockIdx.x;
    const int m = bm & 31;
    const int d = threadIdx.x;
    const double kd = (double)(tensions[m * 64 + d] / masses[m]);
    const double cd = (double)DAMP;
    double Ma = 1.0 - cd * kd, Mb = cd, Mc = -cd * kd, Md = cd;
    #pragma unroll
    for (int it = 0; it < 5; ++it) {             // A^(2^5) = A^32
        const double na = Ma * Ma + Mb * Mc;
        const double nb = Ma * Mb + Mb * Md;
        const double nc = Mc * Ma + Md * Mc;
        const double nd = Mc * Mb + Md * Md;
        Ma = na; Mb = nb; Mc = nc; Md = nd;
    }
    double pos = 0.0, vel = 0.0;
    float* wb = w + (size_t)bm * 64 * 128;
    for (int c = 0; c < 64; ++c) {
        float* row = wb + c * 128;
        const double wp = (double)row[d];
        const double wv = (double)row[64 + d];
        row[d] = (float)pos;                     // entry state of chunk c
        row[64 + d] = (float)vel;
        const double np = Ma * pos + Mb * vel + wp;
        const double nv = Mc * pos + Md * vel + wv;
        pos = np; vel = nv;
    }
}

// ---------------------------------------------------------------------------
// K1c: sim pass 2 — 32-step emit from precomputed entry state, two 16-ts
// quarter stages. LDS 8.9 KB.  [r10-verified]
// ---------------------------------------------------------------------------
__global__ __launch_bounds__(64) void sim_pass2(const float* __restrict__ forces,
                                                const float* __restrict__ hmod,
                                                const float* __restrict__ home,
                                                const float* __restrict__ masses,
                                                const float* __restrict__ tensions,
                                                const float* __restrict__ gains,
                                                const float* __restrict__ mics,
                                                const float* __restrict__ w,
                                                float* __restrict__ disp,
                                                float* __restrict__ rec) {
    const int blk = blockIdx.x;
    const int bm = blk >> 6, c = blk & 63;
    const int m = bm & 31;
    const int d = threadIdx.x;
    const int t0 = c * 32;
    __shared__ __align__(16) float ft[64][17];
    __shared__ __align__(16) float ht[64][17];
    const float k = tensions[m * 64 + d] / masses[m];
    const float gain = gains[m];
    const float mic = mics[m * 64 + d];
    const float hd = home[d];

    float pos = w[(size_t)blk * 128 + d];
    float vel = w[(size_t)blk * 128 + 64 + d];

    #pragma unroll
    for (int phase = 0; phase < 2; ++phase) {
        const int t0p = t0 + phase * 16;
        for (int i = d; i < 256; i += 64) {
            const int dd = i >> 2, q = (i & 3) * 4;
            const size_t off = ((size_t)bm * 64 + dd) * 2048 + t0p + q;
            *(float4*)&ft[dd][q] = *(const float4*)(forces + off);
            *(float4*)&ht[dd][q] = *(const float4*)(hmod + off);
        }
        __syncthreads();
        #pragma unroll
        for (int ts = 0; ts < 16; ++ts) {
            const float f = ft[d][ts];
            const float h = hd + ht[d][ts];
            const float dir = h - pos;
            const float acc = f + k * dir;
            vel = (vel + acc) * DAMP;
            pos = pos + vel;
            ft[d][ts] = dir;                        // disp tile (in place)
            const float x = vel * gain;
            const float e = __expf(2.f * x);
            ht[d][ts] = (1.f - 2.f / (e + 1.f)) * mic;   // prod tile (in place)
        }
        __syncthreads();
        for (int i = d; i < 256; i += 64) {
            const int dd = i >> 2, q = (i & 3) * 4;
            const size_t off = ((size_t)bm * 64 + dd) * 2048 + t0p + q;
            *(float4*)(disp + off) = *(float4*)&ft[dd][q];
        }
        {
            const int ts = d & 15, part = d >> 4;
            float s = 0.f;
            #pragma unroll
            for (int j = 0; j < 16; ++j) s += ht[16 * part + j][ts];
            s += __shfl_xor(s, 16);
            s += __shfl_xor(s, 32);
            if (d < 16) rec[(size_t)bm * 2048 + t0p + d] = s;
        }
        __syncthreads();
    }
}

// ---------------------------------------------------------------------------
// K2: mixture (fp32 acc -> bf16). [unchanged]
// ---------------------------------------------------------------------------
__global__ __launch_bounds__(256) void mix_kernel(const float* __restrict__ disp,
                                                  const float* __restrict__ tofm,
                                                  unsigned short* __restrict__ mixture) {
    __shared__ __align__(16) float tf[64][16];
    const int tid = threadIdx.x;
    for (int i = tid; i < 1024; i += 256) tf[i >> 4][i & 15] = tofm[i];
    __syncthreads();
    const int bm = blockIdx.y;
    const int t = blockIdx.x * 256 + tid;
    float acc[16];
    #pragma unroll
    for (int f = 0; f < 16; ++f) acc[f] = 0.f;
    for (int d = 0; d < 64; ++d) {
        const float v = disp[((size_t)bm * 64 + d) * 2048 + t];
        const float4* r4 = (const float4*)tf[d];
        const float4 a4 = r4[0], b4 = r4[1], c4 = r4[2], d4 = r4[3];
        acc[0]  += v * a4.x; acc[1]  += v * a4.y; acc[2]  += v * a4.z; acc[3]  += v * a4.w;
        acc[4]  += v * b4.x; acc[5]  += v * b4.y; acc[6]  += v * b4.z; acc[7]  += v * b4.w;
        acc[8]  += v * c4.x; acc[9]  += v * c4.y; acc[10] += v * c4.z; acc[11] += v * c4.w;
        acc[12] += v * d4.x; acc[13] += v * d4.y; acc[14] += v * d4.z; acc[15] += v * d4.w;
    }
    #pragma unroll
    for (int f = 0; f < 16; ++f)
        mixture[((size_t)bm * 16 + f) * 2048 + t] = f2bf(acc[f]);
}

// ---------------------------------------------------------------------------
// K3 (MFMA): fft_resample — 2-chunk DirRev staging, bf16 up output.
// [unchanged r14]
// ---------------------------------------------------------------------------
#define DR_STRIDE 2064u           // 1024 bf16 + 16B pad; == 16 mod 128
#define W_STRIDE  5136u
#define W_OFF     33024u          // 16*2064
#define RS_SMEM   74112u          // + 8*5136

__global__ __launch_bounds__(256) void resample_kernel(const float* __restrict__ rec,
                                                       const unsigned short* __restrict__ dirrev,
                                                       unsigned short* __restrict__ upb) {
    const int bm = blockIdx.x;
    const int Q0 = blockIdx.y * 512;
    const int tid = threadIdx.x;
    __shared__ __align__(16) unsigned char smem[RS_SMEM];

    for (int x = tid; x < 2560; x += 256) {
        const int g = (Q0 + x + 1) & 2047;
        const unsigned short bv = f2bf(rec[(size_t)bm * 2048 + g]);
        #pragma unroll
        for (int sg = 0; sg < 8; ++sg) {
            const int y = x - sg;
            if (y >= 0) *(unsigned short*)(smem + W_OFF + sg * W_STRIDE + 2 * y) = bv;
        }
    }

    const int lane = tid & 63;
    const int wv = tid >> 6;
    const int i15 = lane & 15;
    const int g4 = lane >> 4;

    f32x4 acc[8];
    #pragma unroll
    for (int i = 0; i < 8; ++i) acc[i] = (f32x4){0.f, 0.f, 0.f, 0.f};

    const unsigned abase = (unsigned)i15 * DR_STRIDE + 16u * g4;
    const unsigned bbase = W_OFF + (unsigned)(i15 & 7) * W_STRIDE + 16u * (i15 >> 3) + 16u * g4;

    for (int kc = 0; kc < 2; ++kc) {
        if (kc) __syncthreads();
        for (int i = tid; i < 2048; i += 256) {
            const int p = i >> 7, c16 = i & 127;
            *(uint4*)(smem + (unsigned)p * DR_STRIDE + 16u * c16) =
                *(const uint4*)(dirrev + (size_t)p * 2048 + kc * 1024 + 8 * c16);
        }
        __syncthreads();

        for (int kkb = 0; kkb < 4; ++kkb) {
            bf16x8 afr[8];
            #pragma unroll
            for (int kj = 0; kj < 8; ++kj)
                afr[kj] = *(const bf16x8*)(smem + abase + 64u * (kkb * 8 + kj));
            #pragma unroll
            for (int qtl = 0; qtl < 8; ++qtl) {
                const int qt = wv * 8 + qtl;
                const unsigned bb = bbase + 32u * qt + 2048u * kc;
                #pragma unroll
                for (int kj = 0; kj < 8; ++kj) {
                    const bf16x8 bfr = *(const bf16x8*)(smem + bb + 64u * (kkb * 8 + kj));
                    acc[qtl] = __builtin_amdgcn_mfma_f32_16x16x32_bf16(afr[kj], bfr, acc[qtl], 0, 0, 0);
                }
            }
        }
    }

    #pragma unroll
    for (int qtl = 0; qtl < 8; ++qtl) {
        const int qt = wv * 8 + qtl;
        const int q = Q0 + 16 * qt + i15;
        const int sbase = 16 * q + 4 * g4;
        const unsigned jb = (unsigned)bm * 32768u + (unsigned)sbase;
        u16x4 o;
        o[0] = f2bf(fabsf(acc[qtl][0] * (1.f / 8192.f)) * noise_at(jb));
        o[1] = f2bf(fabsf(acc[qtl][1] * (1.f / 8192.f)) * noise_at(jb + 1u));
        o[2] = f2bf(fabsf(acc[qtl][2] * (1.f / 8192.f)) * noise_at(jb + 2u));
        o[3] = f2bf(fabsf(acc[qtl][3] * (1.f / 8192.f)) * noise_at(jb + 3u));
        *(u16x4*)(upb + (size_t)bm * 32768 + sbase) = o;
    }
}

// ---------------------------------------------------------------------------
// K4 (MFMA): hf — rolling B-fragment register buffer: tile g and g+1 share
// 8 of 16 fragments (j = 8g+kk addressing), so keep 16 slots (slot = j&15)
// and load only the 8 new fragments per tile: 40 LDS reads per rr instead
// of 64 (-37.5%). Addresses identical to r10-verified version.
// grid (32 s-tiles of 1024, 64 bm), 256 threads.
// ---------------------------------------------------------------------------
#define W_STR2   3088u            // 1544 bf16, padded (1536 used)
#define MX_OFF   24704u           // 8*3088
#define HF_SMEM  26880u           // + 16*68*2

__global__ __launch_bounds__(256) void hf_kernel(const unsigned short* __restrict__ upb,
                                                 const unsigned short* __restrict__ fnrev,
                                                 const unsigned short* __restrict__ mixture,
                                                 float* __restrict__ hf) {
    const int tile = blockIdx.x;     // 0..31
    const int bm = blockIdx.y;       // 0..63
    const int b = bm >> 5;
    const int S0 = tile * 1024;
    const int tbase = tile * 64 - 1;
    const int tid = threadIdx.x;

    __shared__ __align__(16) unsigned char smem[HF_SMEM];
    unsigned short* mixl = (unsigned short*)(smem + MX_OFF);

    // stage 8 shifted copies: W[x] = upb[S0-511+x], x in [0,1536)
    for (int x = tid; x < 1536; x += 256) {
        const int gidx = S0 - 511 + x;
        const unsigned short v = (gidx >= 0) ? upb[(size_t)bm * 32768 + gidx]
                                             : (unsigned short)0;
        #pragma unroll
        for (int sg = 0; sg < 8; ++sg) {
            const int y = x - sg;
            if (y >= 0) *(unsigned short*)(smem + sg * W_STR2 + 2 * y) = v;
        }
    }
    // stage mixl window (bf16): 16 f x 66 t
    for (int i = tid; i < 16 * 66; i += 256) {
        const int f = i / 66, tt = i - f * 66;
        const int t = tbase + tt;
        mixl[f * 68 + tt] = (t >= 0 && t < 2048)
            ? mixture[((size_t)bm * 16 + f) * 2048 + t] : (unsigned short)0;
    }
    // A-fragments from fnrev (L2-cached, 16B aligned loads)
    const int lane = tid & 63;
    const int i15 = lane & 15;
    const int g4 = lane >> 4;
    const int wv = tid >> 6;
    bf16x8 afr[16];
    #pragma unroll
    for (int kk = 0; kk < 16; ++kk)
        afr[kk] = *(const bf16x8*)(fnrev + (size_t)(b * 16 + i15) * 512 + 32 * kk + 8 * g4);
    __syncthreads();

    for (int rr = 0; rr < 4; ++rr) {
        const int rho = wv * 4 + rr;            // s residue 0..15
        const int sig = rho & 7;
        const unsigned baseR = (unsigned)sig * W_STR2 + 2u * (rho - sig)
                             + 32u * i15 + 16u * g4;
        // rolling window fragment buffer: frag j lives in slot j & 15
        bf16x8 wfr[16];
        #pragma unroll
        for (int j = 0; j < 8; ++j)
            wfr[j] = *(const bf16x8*)(smem + baseR + 64u * j);
        #pragma unroll
        for (int g = 0; g < 4; ++g) {
            #pragma unroll
            for (int jj = 0; jj < 8; ++jj) {
                const int j = 8 * g + 8 + jj;
                wfr[j & 15] = *(const bf16x8*)(smem + baseR + 64u * (unsigned)j);
            }
            f32x4 acc = {0.f, 0.f, 0.f, 0.f};
            #pragma unroll
            for (int kk = 0; kk < 16; ++kk)
                acc = __builtin_amdgcn_mfma_f32_16x16x32_bf16(afr[kk], wfr[(8 * g + kk) & 15], acc, 0, 0, 0);
            const int s = S0 + 256 * g + rho + 16 * i15;
            float posf = ((float)s + 0.5f) * 0.0625f - 0.5f;
            posf = fminf(fmaxf(posf, 0.f), 2047.f);
            const int i0 = (int)posf;
            const float wg = posf - (float)i0;
            const int i1 = min(i0 + 1, 2047);
            const int t0 = i0 - tbase, t1 = i1 - tbase;
            float part = 0.f;
            #pragma unroll
            for (int r = 0; r < 4; ++r) {
                const int f = 4 * g4 + r;
                const float mv = bf2f(mixl[f * 68 + t0]) * (1.f - wg)
                               + bf2f(mixl[f * 68 + t1]) * wg;
                part += mv * acc[r];
            }
            part += __shfl_xor(part, 16);
            part += __shfl_xor(part, 32);
            if (g4 == 0) {
                const int e = 511 + 256 * g + rho + 16 * i15;   // copy-0 element
                const float upv = bf2f(*(const unsigned short*)(smem + 2 * e));
                hf[(size_t)bm * 32768 + s] = part + upv;
            }
        }
    }
}

// ---------------------------------------------------------------------------
// Launch
// ---------------------------------------------------------------------------
extern "C" void kernel_launch(void* const* d_in, const int* in_sizes, int n_in,
                              void* d_out, int out_size, void* d_ws, size_t ws_size,
                              hipStream_t stream) {
    const float* forces   = (const float*)d_in[0];
    const float* hmod     = (const float*)d_in[1];
    const float* filters  = (const float*)d_in[2];
    const float* home     = (const float*)d_in[3];
    const float* masses   = (const float*)d_in[4];
    const float* tensions = (const float*)d_in[5];
    const float* gains    = (const float*)d_in[6];
    const float* mics     = (const float*)d_in[7];
    const float* tofm     = (const float*)d_in[8];

    float* out  = (float*)d_out;
    float* rec  = out;                  // 131072
    float* disp = out + 131072;         // 8388608
    float* hf   = out + 8519680;        // 2097152

    unsigned short* upb     = (unsigned short*)d_ws;                    // 2097152 bf16 (4MB)
    unsigned short* mixture = (unsigned short*)((float*)d_ws + 1048576);// 2097152 bf16 (4MB)
    unsigned short* dirrev  = (unsigned short*)((float*)d_ws + 2097152);// 32768 bf16
    float* w                = (float*)d_ws + 2113536;                   // 524288 f32 (2MB)
    unsigned short* fnrev   = (unsigned short*)((float*)d_ws + 2637824);// 16384 bf16
    // total ws use ~10.2 MB

    sim_pass1<<<4640, 64, 0, stream>>>(forces, hmod, home, masses, tensions, w,
                                       filters, dirrev, fnrev);
    sim_scan<<<64, 64, 0, stream>>>(masses, tensions, w);
    sim_pass2<<<4096, 64, 0, stream>>>(forces, hmod, home, masses, tensions, gains, mics, w, disp, rec);
    mix_kernel<<<dim3(8, 64), 256, 0, stream>>>(disp, tofm, mixture);
    resample_kernel<<<dim3(64, 4), 256, 0, stream>>>(rec, dirrev, upb);
    hf_kernel<<<dim3(32, 64), 256, 0, stream>>>(upb, fnrev, mixture, hf);
}